// Round 1
// baseline (5946.187 us; speedup 1.0000x reference)
//
#include <hip/hip_runtime.h>

#define N_NODES 30000
#define N_EDGES 240000
#define NF 32
#define EF 16
#define HF 64
#define NC 8

// ---------------------------------------------------------------------------
// h_n = node_feat @ Wn + bn          [N,32]@[32,64]
// ---------------------------------------------------------------------------
__global__ void __launch_bounds__(256) node_init_kernel(
    const float* __restrict__ node_feat, const float* __restrict__ Wn,
    const float* __restrict__ bn, float* __restrict__ h_n) {
  int n = blockIdx.x * 256 + threadIdx.x;
  if (n >= N_NODES) return;
  float x[NF];
  const float4* xp = (const float4*)(node_feat + n * NF);
#pragma unroll
  for (int k4 = 0; k4 < NF / 4; ++k4) {
    float4 v = xp[k4];
    x[4 * k4 + 0] = v.x; x[4 * k4 + 1] = v.y; x[4 * k4 + 2] = v.z; x[4 * k4 + 3] = v.w;
  }
  float h[HF];
#pragma unroll
  for (int j = 0; j < HF; ++j) h[j] = bn[j];
#pragma unroll
  for (int k = 0; k < NF; ++k) {
    float xk = x[k];
#pragma unroll
    for (int j = 0; j < HF; ++j) h[j] = fmaf(xk, Wn[k * HF + j], h[j]);
  }
  float4* hp = (float4*)(h_n + n * HF);
#pragma unroll
  for (int j4 = 0; j4 < HF / 4; ++j4)
    hp[j4] = make_float4(h[4 * j4], h[4 * j4 + 1], h[4 * j4 + 2], h[4 * j4 + 3]);
}

// ---------------------------------------------------------------------------
// s0 += edge_feat[e] scattered to dst;  deg[dst] += 1
// ---------------------------------------------------------------------------
__global__ void __launch_bounds__(256) scatter_init_kernel(
    const float* __restrict__ edge_feat, const int* __restrict__ dst,
    float* __restrict__ s0, float* __restrict__ deg) {
  int e = blockIdx.x * 256 + threadIdx.x;
  if (e >= N_EDGES) return;
  int d = dst[e];
  const float4* ep = (const float4*)(edge_feat + e * EF);
  float* sp = s0 + d * EF;
#pragma unroll
  for (int k4 = 0; k4 < EF / 4; ++k4) {
    float4 v = ep[k4];
    atomicAdd(sp + 4 * k4 + 0, v.x);
    atomicAdd(sp + 4 * k4 + 1, v.y);
    atomicAdd(sp + 4 * k4 + 2, v.z);
    atomicAdd(sp + 4 * k4 + 3, v.w);
  }
  atomicAdd(deg + d, 1.0f);
}

// ---------------------------------------------------------------------------
// Fused edge pass:
//   h_e   = e_in @ We + be                          (registers only)
//   e_out = sigmoid([h_n[src], h_e, h_n[dst]] @ Wem + bem)
//   s_next[dst] += e_out   (atomic, feeds NEXT iteration's node aggregation)
// ---------------------------------------------------------------------------
__global__ void __launch_bounds__(256) edge_kernel(
    const float* __restrict__ e_in, float* __restrict__ e_out,
    const float* __restrict__ h_n,
    const int* __restrict__ src, const int* __restrict__ dst,
    const float* __restrict__ We, const float* __restrict__ be,
    const float* __restrict__ Wem, const float* __restrict__ bem,
    float* __restrict__ s_next) {
  int e = blockIdx.x * 256 + threadIdx.x;
  if (e >= N_EDGES) return;
  int sidx = src[e], didx = dst[e];
  const float4* hsp = (const float4*)(h_n + sidx * HF);
  const float4* hdp = (const float4*)(h_n + didx * HF);

  float ein[EF];
  const float4* ep = (const float4*)(e_in + e * EF);
#pragma unroll
  for (int k4 = 0; k4 < EF / 4; ++k4) {
    float4 v = ep[k4];
    ein[4 * k4 + 0] = v.x; ein[4 * k4 + 1] = v.y; ein[4 * k4 + 2] = v.z; ein[4 * k4 + 3] = v.w;
  }

  float z[EF];
#pragma unroll
  for (int j = 0; j < EF; ++j) z[j] = bem[j];

  // src-node contribution: Wem rows [0,64)
#pragma unroll
  for (int k4 = 0; k4 < HF / 4; ++k4) {
    float4 hv = hsp[k4];
    float hv4[4] = {hv.x, hv.y, hv.z, hv.w};
#pragma unroll
    for (int t = 0; t < 4; ++t) {
#pragma unroll
      for (int j = 0; j < EF; ++j)
        z[j] = fmaf(hv4[t], Wem[(4 * k4 + t) * EF + j], z[j]);
    }
  }

  // h_e = e_in @ We + be (in registers)
  float he[HF];
#pragma unroll
  for (int j = 0; j < HF; ++j) he[j] = be[j];
#pragma unroll
  for (int k = 0; k < EF; ++k) {
    float ek = ein[k];
#pragma unroll
    for (int j = 0; j < HF; ++j) he[j] = fmaf(ek, We[k * HF + j], he[j]);
  }
  // h_e contribution: Wem rows [64,128)
#pragma unroll
  for (int k = 0; k < HF; ++k) {
    float hk = he[k];
#pragma unroll
    for (int j = 0; j < EF; ++j)
      z[j] = fmaf(hk, Wem[(HF + k) * EF + j], z[j]);
  }

  // dst-node contribution: Wem rows [128,192)
#pragma unroll
  for (int k4 = 0; k4 < HF / 4; ++k4) {
    float4 hv = hdp[k4];
    float hv4[4] = {hv.x, hv.y, hv.z, hv.w};
#pragma unroll
    for (int t = 0; t < 4; ++t) {
#pragma unroll
      for (int j = 0; j < EF; ++j)
        z[j] = fmaf(hv4[t], Wem[(2 * HF + 4 * k4 + t) * EF + j], z[j]);
    }
  }

#pragma unroll
  for (int j = 0; j < EF; ++j) z[j] = 1.0f / (1.0f + __expf(-z[j]));

  float4* eop = (float4*)(e_out + e * EF);
#pragma unroll
  for (int j4 = 0; j4 < EF / 4; ++j4)
    eop[j4] = make_float4(z[4 * j4], z[4 * j4 + 1], z[4 * j4 + 2], z[4 * j4 + 3]);

  float* sp = s_next + didx * EF;
#pragma unroll
  for (int j = 0; j < EF; ++j) atomicAdd(sp + j, z[j]);
}

// ---------------------------------------------------------------------------
// Fused node pass (in-place on h_n):
//   agg  = s_cur @ We + deg*be         (segment_sum pushed through the linear)
//   nin  = sigmoid([agg, h_n] @ Wnm + bnm)
//   h_n' = nin @ Wn + bn
// ---------------------------------------------------------------------------
__global__ void __launch_bounds__(256) node_kernel(
    float* __restrict__ h_n, const float* __restrict__ s_cur,
    const float* __restrict__ deg,
    const float* __restrict__ We, const float* __restrict__ be,
    const float* __restrict__ Wnm, const float* __restrict__ bnm,
    const float* __restrict__ Wn, const float* __restrict__ bn) {
  int n = blockIdx.x * 256 + threadIdx.x;
  if (n >= N_NODES) return;
  float s[EF];
  const float4* sp = (const float4*)(s_cur + n * EF);
#pragma unroll
  for (int k4 = 0; k4 < EF / 4; ++k4) {
    float4 v = sp[k4];
    s[4 * k4 + 0] = v.x; s[4 * k4 + 1] = v.y; s[4 * k4 + 2] = v.z; s[4 * k4 + 3] = v.w;
  }
  float dg = deg[n];

  float z[NF];
#pragma unroll
  for (int i = 0; i < NF; ++i) z[i] = bnm[i];

  // agg contribution (streamed one j at a time; agg never materialized)
#pragma unroll
  for (int j = 0; j < HF; ++j) {
    float aj = dg * be[j];
#pragma unroll
    for (int k = 0; k < EF; ++k) aj = fmaf(s[k], We[k * HF + j], aj);
#pragma unroll
    for (int i = 0; i < NF; ++i) z[i] = fmaf(aj, Wnm[j * NF + i], z[i]);
  }

  // own-h contribution (streamed)
  const float4* hp = (const float4*)(h_n + n * HF);
#pragma unroll
  for (int j4 = 0; j4 < HF / 4; ++j4) {
    float4 hv = hp[j4];
    float hv4[4] = {hv.x, hv.y, hv.z, hv.w};
#pragma unroll
    for (int t = 0; t < 4; ++t) {
      int j = 4 * j4 + t;
#pragma unroll
      for (int i = 0; i < NF; ++i)
        z[i] = fmaf(hv4[t], Wnm[(HF + j) * NF + i], z[i]);
    }
  }

#pragma unroll
  for (int i = 0; i < NF; ++i) z[i] = 1.0f / (1.0f + __expf(-z[i]));

  float h2[HF];
#pragma unroll
  for (int j = 0; j < HF; ++j) h2[j] = bn[j];
#pragma unroll
  for (int i = 0; i < NF; ++i) {
    float zi = z[i];
#pragma unroll
    for (int j = 0; j < HF; ++j) h2[j] = fmaf(zi, Wn[i * HF + j], h2[j]);
  }
  float4* hop = (float4*)(h_n + n * HF);
#pragma unroll
  for (int j4 = 0; j4 < HF / 4; ++j4)
    hop[j4] = make_float4(h2[4 * j4], h2[4 * j4 + 1], h2[4 * j4 + 2], h2[4 * j4 + 3]);
}

// ---------------------------------------------------------------------------
// out = h_n @ Wfc + bfc              [N,64]@[64,8]
// ---------------------------------------------------------------------------
__global__ void __launch_bounds__(256) out_kernel(
    const float* __restrict__ h_n, const float* __restrict__ Wfc,
    const float* __restrict__ bfc, float* __restrict__ out) {
  int n = blockIdx.x * 256 + threadIdx.x;
  if (n >= N_NODES) return;
  float o[NC];
#pragma unroll
  for (int c = 0; c < NC; ++c) o[c] = bfc[c];
  const float4* hp = (const float4*)(h_n + n * HF);
#pragma unroll
  for (int j4 = 0; j4 < HF / 4; ++j4) {
    float4 hv = hp[j4];
    float hv4[4] = {hv.x, hv.y, hv.z, hv.w};
#pragma unroll
    for (int t = 0; t < 4; ++t) {
#pragma unroll
      for (int c = 0; c < NC; ++c)
        o[c] = fmaf(hv4[t], Wfc[(4 * j4 + t) * NC + c], o[c]);
    }
  }
  float4* op = (float4*)(out + n * NC);
  op[0] = make_float4(o[0], o[1], o[2], o[3]);
  op[1] = make_float4(o[4], o[5], o[6], o[7]);
}

extern "C" void kernel_launch(void* const* d_in, const int* in_sizes, int n_in,
                              void* d_out, int out_size, void* d_ws, size_t ws_size,
                              hipStream_t stream) {
  const float* node_feat = (const float*)d_in[0];
  const float* edge_feat = (const float*)d_in[1];
  const int*   src       = (const int*)d_in[2];
  const int*   dst       = (const int*)d_in[3];
  const float* Wn  = (const float*)d_in[4];
  const float* bn  = (const float*)d_in[5];
  const float* We  = (const float*)d_in[6];
  const float* be  = (const float*)d_in[7];
  const float* Wem = (const float*)d_in[8];
  const float* bem = (const float*)d_in[9];
  const float* Wnm = (const float*)d_in[10];
  const float* bnm = (const float*)d_in[11];
  const float* Wfc = (const float*)d_in[12];
  const float* bfc = (const float*)d_in[13];
  float* out = (float*)d_out;

  float* ws   = (float*)d_ws;
  float* h_n  = ws;                        // 30000*64  = 1,920,000 f
  float* e_ws = h_n + N_NODES * HF;        // 240000*16 = 3,840,000 f
  float* s0   = e_ws + N_EDGES * EF;       // 30000*16  =   480,000 f
  float* s1   = s0 + N_NODES * EF;         //             480,000 f
  float* deg  = s1 + N_NODES * EF;         //              30,000 f
  float* sbuf[2] = {s0, s1};

  const int EB = (N_EDGES + 255) / 256;
  const int NB = (N_NODES + 255) / 256;

  hipMemsetAsync(s0, 0, (size_t)N_NODES * EF * sizeof(float), stream);
  hipMemsetAsync(deg, 0, (size_t)N_NODES * sizeof(float), stream);
  scatter_init_kernel<<<EB, 256, 0, stream>>>(edge_feat, dst, s0, deg);
  node_init_kernel<<<NB, 256, 0, stream>>>(node_feat, Wn, bn, h_n);

  // Reference runs 13 iterations, but iteration 13's edge+node updates are
  // dead (output = h_n(13) = n_in(12)@Wn+bn), and iteration 12's edge update
  // only matters through its scatter: run 11 edge passes + 12 node passes.
  for (int i = 1; i <= 12; ++i) {
    if (i <= 11) {
      float* s_next = sbuf[i & 1];
      hipMemsetAsync(s_next, 0, (size_t)N_NODES * EF * sizeof(float), stream);
      edge_kernel<<<EB, 256, 0, stream>>>(
          (i == 1) ? edge_feat : e_ws, e_ws, h_n, src, dst,
          We, be, Wem, bem, s_next);
    }
    node_kernel<<<NB, 256, 0, stream>>>(
        h_n, sbuf[(i - 1) & 1], deg, We, be, Wnm, bnm, Wn, bn);
  }

  out_kernel<<<NB, 256, 0, stream>>>(h_n, Wfc, bfc, out);
}

// Round 2
// 3219.165 us; speedup vs baseline: 1.8471x; 1.8471x over previous
//
#include <hip/hip_runtime.h>

#define N_NODES 30000
#define N_EDGES 240000
#define NF 32
#define EF 16
#define HF 64
#define NC 8

__device__ __forceinline__ float sigmoidf_(float x) {
  return 1.0f / (1.0f + __expf(-x));
}

// ---------------------------------------------------------------------------
// Precompute folded weight products (h_e is never materialized):
//   Wcomb[16][16] = We @ Wem[64:128]      bcomb[16] = bem + be @ Wem[64:128]
//   Wnc  [16][32] = We @ Wnm[0:64]        bvec[32]  = be @ Wnm[0:64]
// ---------------------------------------------------------------------------
__global__ void __launch_bounds__(256) precompute_kernel(
    const float* __restrict__ We, const float* __restrict__ be,
    const float* __restrict__ Wem, const float* __restrict__ bem,
    const float* __restrict__ Wnm,
    float* __restrict__ Wcomb, float* __restrict__ bcomb,
    float* __restrict__ Wnc, float* __restrict__ bvec) {
  int tid = threadIdx.x;
  // Wcomb: 256 elements, one per thread
  {
    int k = tid >> 4, i = tid & 15;
    float acc = 0.0f;
    for (int j = 0; j < HF; ++j)
      acc = fmaf(We[k * HF + j], Wem[(HF + j) * EF + i], acc);
    Wcomb[k * EF + i] = acc;
  }
  // Wnc: 512 elements, two per thread
  for (int idx = tid; idx < EF * NF; idx += 256) {
    int k = idx >> 5, i = idx & 31;
    float acc = 0.0f;
    for (int j = 0; j < HF; ++j)
      acc = fmaf(We[k * HF + j], Wnm[j * NF + i], acc);
    Wnc[idx] = acc;
  }
  if (tid < EF) {
    float acc = bem[tid];
    for (int j = 0; j < HF; ++j)
      acc = fmaf(be[j], Wem[(HF + j) * EF + tid], acc);
    bcomb[tid] = acc;
  }
  if (tid < NF) {
    float acc = 0.0f;
    for (int j = 0; j < HF; ++j)
      acc = fmaf(be[j], Wnm[j * NF + tid], acc);
    bvec[tid] = acc;
  }
}

// ---------------------------------------------------------------------------
// h_n = node_feat @ Wn + bn          [N,32]@[32,64]   (once per launch)
// ---------------------------------------------------------------------------
__global__ void __launch_bounds__(256) node_init_kernel(
    const float* __restrict__ node_feat, const float* __restrict__ Wn,
    const float* __restrict__ bn, float* __restrict__ h_n) {
  __shared__ float sW[NF * HF];
  __shared__ float sB[HF];
  for (int idx = threadIdx.x; idx < NF * HF; idx += 256) sW[idx] = Wn[idx];
  if (threadIdx.x < HF) sB[threadIdx.x] = bn[threadIdx.x];
  __syncthreads();
  int gid = blockIdx.x * 256 + threadIdx.x;
  int n = gid >> 1, p = gid & 1;   // 2 threads per node, each does 32 outputs
  if (n >= N_NODES) return;
  const int jbase = 32 * p;
  float h[32];
#pragma unroll
  for (int j = 0; j < 32; ++j) h[j] = sB[jbase + j];
  const float4* xp = (const float4*)(node_feat + n * NF);
  for (int k4 = 0; k4 < NF / 4; ++k4) {
    float4 v = xp[k4];
    float vv[4] = {v.x, v.y, v.z, v.w};
#pragma unroll
    for (int t = 0; t < 4; ++t) {
      const float4* wr = (const float4*)(sW + (4 * k4 + t) * HF + jbase);
#pragma unroll
      for (int j4 = 0; j4 < 8; ++j4) {
        float4 w = wr[j4];
        h[4 * j4 + 0] = fmaf(vv[t], w.x, h[4 * j4 + 0]);
        h[4 * j4 + 1] = fmaf(vv[t], w.y, h[4 * j4 + 1]);
        h[4 * j4 + 2] = fmaf(vv[t], w.z, h[4 * j4 + 2]);
        h[4 * j4 + 3] = fmaf(vv[t], w.w, h[4 * j4 + 3]);
      }
    }
  }
  float4* hp = (float4*)(h_n + n * HF + jbase);
#pragma unroll
  for (int j4 = 0; j4 < 8; ++j4)
    hp[j4] = make_float4(h[4 * j4], h[4 * j4 + 1], h[4 * j4 + 2], h[4 * j4 + 3]);
}

// ---------------------------------------------------------------------------
// s0 += edge_feat[e] scattered to dst;  deg[dst] += 1
// ---------------------------------------------------------------------------
__global__ void __launch_bounds__(256) scatter_init_kernel(
    const float* __restrict__ edge_feat, const int* __restrict__ dst,
    float* __restrict__ s0, float* __restrict__ deg) {
  int e = blockIdx.x * 256 + threadIdx.x;
  if (e >= N_EDGES) return;
  int d = dst[e];
  const float4* ep = (const float4*)(edge_feat + e * EF);
  float* sp = s0 + d * EF;
#pragma unroll
  for (int k4 = 0; k4 < EF / 4; ++k4) {
    float4 v = ep[k4];
    atomicAdd(sp + 4 * k4 + 0, v.x);
    atomicAdd(sp + 4 * k4 + 1, v.y);
    atomicAdd(sp + 4 * k4 + 2, v.z);
    atomicAdd(sp + 4 * k4 + 3, v.w);
  }
  atomicAdd(deg + d, 1.0f);
}

// ---------------------------------------------------------------------------
// Fused edge pass (h_e folded away):
//   z     = bcomb + e_in@Wcomb + h_n[src]@WemS + h_n[dst]@WemD
//   e_out = sigmoid(z)
//   s_next[dst] += e_out
// ---------------------------------------------------------------------------
__global__ void __launch_bounds__(256) edge_kernel(
    const float* __restrict__ e_in, float* __restrict__ e_out,
    const float* __restrict__ h_n,
    const int* __restrict__ src, const int* __restrict__ dst,
    const float* __restrict__ Wem,
    const float* __restrict__ Wcomb, const float* __restrict__ bcomb,
    float* __restrict__ s_next) {
  __shared__ float sWS[HF * EF];   // Wem rows [0,64)
  __shared__ float sWD[HF * EF];   // Wem rows [128,192)
  __shared__ float sWC[EF * EF];   // Wcomb
  __shared__ float sBC[EF];
  for (int idx = threadIdx.x; idx < HF * EF; idx += 256) {
    sWS[idx] = Wem[idx];
    sWD[idx] = Wem[2 * HF * EF + idx];
  }
  for (int idx = threadIdx.x; idx < EF * EF; idx += 256) sWC[idx] = Wcomb[idx];
  if (threadIdx.x < EF) sBC[threadIdx.x] = bcomb[threadIdx.x];
  __syncthreads();

  int e = blockIdx.x * 256 + threadIdx.x;
  if (e >= N_EDGES) return;
  int sidx = src[e], didx = dst[e];

  float z[EF];
#pragma unroll
  for (int i = 0; i < EF; ++i) z[i] = sBC[i];

  // e_in @ Wcomb  (16x16)
  const float4* ep = (const float4*)(e_in + e * EF);
  for (int k4 = 0; k4 < EF / 4; ++k4) {
    float4 v = ep[k4];
    float vv[4] = {v.x, v.y, v.z, v.w};
#pragma unroll
    for (int t = 0; t < 4; ++t) {
      const float4* wr = (const float4*)(sWC + (4 * k4 + t) * EF);
#pragma unroll
      for (int i4 = 0; i4 < 4; ++i4) {
        float4 w = wr[i4];
        z[4 * i4 + 0] = fmaf(vv[t], w.x, z[4 * i4 + 0]);
        z[4 * i4 + 1] = fmaf(vv[t], w.y, z[4 * i4 + 1]);
        z[4 * i4 + 2] = fmaf(vv[t], w.z, z[4 * i4 + 2]);
        z[4 * i4 + 3] = fmaf(vv[t], w.w, z[4 * i4 + 3]);
      }
    }
  }

  // gathered node contributions (rolled outer loop keeps code small)
  const float4* hsp = (const float4*)(h_n + sidx * HF);
  const float4* hdp = (const float4*)(h_n + didx * HF);
  for (int j4 = 0; j4 < HF / 4; ++j4) {
    float4 a = hsp[j4];
    float4 b = hdp[j4];
    float av[4] = {a.x, a.y, a.z, a.w};
    float bv[4] = {b.x, b.y, b.z, b.w};
#pragma unroll
    for (int t = 0; t < 4; ++t) {
      const float4* wsr = (const float4*)(sWS + (4 * j4 + t) * EF);
      const float4* wdr = (const float4*)(sWD + (4 * j4 + t) * EF);
#pragma unroll
      for (int i4 = 0; i4 < 4; ++i4) {
        float4 ws = wsr[i4];
        float4 wd = wdr[i4];
        z[4 * i4 + 0] = fmaf(av[t], ws.x, fmaf(bv[t], wd.x, z[4 * i4 + 0]));
        z[4 * i4 + 1] = fmaf(av[t], ws.y, fmaf(bv[t], wd.y, z[4 * i4 + 1]));
        z[4 * i4 + 2] = fmaf(av[t], ws.z, fmaf(bv[t], wd.z, z[4 * i4 + 2]));
        z[4 * i4 + 3] = fmaf(av[t], ws.w, fmaf(bv[t], wd.w, z[4 * i4 + 3]));
      }
    }
  }

#pragma unroll
  for (int i = 0; i < EF; ++i) z[i] = sigmoidf_(z[i]);

  float4* eop = (float4*)(e_out + e * EF);
#pragma unroll
  for (int i4 = 0; i4 < EF / 4; ++i4)
    eop[i4] = make_float4(z[4 * i4], z[4 * i4 + 1], z[4 * i4 + 2], z[4 * i4 + 3]);

  float* sp = s_next + didx * EF;
#pragma unroll
  for (int i = 0; i < EF; ++i) atomicAdd(sp + i, z[i]);
}

// ---------------------------------------------------------------------------
// Fused node pass, 2 threads per node (in-place on h_n):
//   z    = bnm + deg*bvec + s@Wnc + h@WnmBot       (each thread: 16 of 32)
//   exchange halves via shfl, sigmoid
//   h_n' = sigmoid(z) @ Wn + bn                    (each thread: 32 of 64)
// ---------------------------------------------------------------------------
__global__ void __launch_bounds__(256) node_kernel(
    float* __restrict__ h_n, const float* __restrict__ s_cur,
    const float* __restrict__ deg,
    const float* __restrict__ Wnm,     // full [128][32]; rows 64.. used
    const float* __restrict__ Wn, const float* __restrict__ bn,
    const float* __restrict__ bnm,
    const float* __restrict__ Wnc, const float* __restrict__ bvec) {
  __shared__ float sWB[HF * NF];   // WnmBot = Wnm rows [64,128)
  __shared__ float sWN[NF * HF];   // Wn
  __shared__ float sWC[EF * NF];   // Wnc
  __shared__ float sBN[HF];
  __shared__ float sBM[NF];
  __shared__ float sBV[NF];
  for (int idx = threadIdx.x; idx < HF * NF; idx += 256) {
    sWB[idx] = Wnm[HF * NF + idx];
    sWN[idx] = Wn[idx];
  }
  for (int idx = threadIdx.x; idx < EF * NF; idx += 256) sWC[idx] = Wnc[idx];
  if (threadIdx.x < HF) sBN[threadIdx.x] = bn[threadIdx.x];
  if (threadIdx.x < NF) {
    sBM[threadIdx.x] = bnm[threadIdx.x];
    sBV[threadIdx.x] = bvec[threadIdx.x];
  }
  __syncthreads();

  int gid = blockIdx.x * 256 + threadIdx.x;
  int n = gid >> 1, p = gid & 1;
  if (n >= N_NODES) return;
  const int ibase = 16 * p;    // this thread's 16-wide slice of z[32]

  float dg = deg[n];
  float z[16];
#pragma unroll
  for (int i = 0; i < 16; ++i) z[i] = fmaf(dg, sBV[ibase + i], sBM[ibase + i]);

  // s @ Wnc (16x32, this thread's 16 columns)
  const float4* sp = (const float4*)(s_cur + n * EF);
  for (int k4 = 0; k4 < EF / 4; ++k4) {
    float4 v = sp[k4];
    float vv[4] = {v.x, v.y, v.z, v.w};
#pragma unroll
    for (int t = 0; t < 4; ++t) {
      const float4* wr = (const float4*)(sWC + (4 * k4 + t) * NF + ibase);
#pragma unroll
      for (int i4 = 0; i4 < 4; ++i4) {
        float4 w = wr[i4];
        z[4 * i4 + 0] = fmaf(vv[t], w.x, z[4 * i4 + 0]);
        z[4 * i4 + 1] = fmaf(vv[t], w.y, z[4 * i4 + 1]);
        z[4 * i4 + 2] = fmaf(vv[t], w.z, z[4 * i4 + 2]);
        z[4 * i4 + 3] = fmaf(vv[t], w.w, z[4 * i4 + 3]);
      }
    }
  }

  // h @ WnmBot (64x32, this thread's 16 columns)
  const float4* hp = (const float4*)(h_n + n * HF);
  for (int j4 = 0; j4 < HF / 4; ++j4) {
    float4 v = hp[j4];
    float vv[4] = {v.x, v.y, v.z, v.w};
#pragma unroll
    for (int t = 0; t < 4; ++t) {
      const float4* wr = (const float4*)(sWB + (4 * j4 + t) * NF + ibase);
#pragma unroll
      for (int i4 = 0; i4 < 4; ++i4) {
        float4 w = wr[i4];
        z[4 * i4 + 0] = fmaf(vv[t], w.x, z[4 * i4 + 0]);
        z[4 * i4 + 1] = fmaf(vv[t], w.y, z[4 * i4 + 1]);
        z[4 * i4 + 2] = fmaf(vv[t], w.z, z[4 * i4 + 2]);
        z[4 * i4 + 3] = fmaf(vv[t], w.w, z[4 * i4 + 3]);
      }
    }
  }

  // exchange the other 16 z values from the partner lane (same wave: lane^1)
  float zx[16];
#pragma unroll
  for (int i = 0; i < 16; ++i) zx[i] = __shfl_xor(z[i], 1, 64);
  // rows in Wn: own z[i] -> row ibase+i ; partner zx[i] -> row (16-ibase)+i
  const int xbase = 16 - ibase;

#pragma unroll
  for (int i = 0; i < 16; ++i) z[i] = sigmoidf_(z[i]);
#pragma unroll
  for (int i = 0; i < 16; ++i) zx[i] = sigmoidf_(zx[i]);

  // h2 = sig(z_full) @ Wn + bn, this thread's 32-wide output slice
  const int jbase = 32 * p;
  float h2[32];
#pragma unroll
  for (int j = 0; j < 32; ++j) h2[j] = sBN[jbase + j];
  for (int i = 0; i < 16; ++i) {
    float v = z[i];
    const float4* wr = (const float4*)(sWN + (ibase + i) * HF + jbase);
#pragma unroll
    for (int j4 = 0; j4 < 8; ++j4) {
      float4 w = wr[j4];
      h2[4 * j4 + 0] = fmaf(v, w.x, h2[4 * j4 + 0]);
      h2[4 * j4 + 1] = fmaf(v, w.y, h2[4 * j4 + 1]);
      h2[4 * j4 + 2] = fmaf(v, w.z, h2[4 * j4 + 2]);
      h2[4 * j4 + 3] = fmaf(v, w.w, h2[4 * j4 + 3]);
    }
  }
  for (int i = 0; i < 16; ++i) {
    float v = zx[i];
    const float4* wr = (const float4*)(sWN + (xbase + i) * HF + jbase);
#pragma unroll
    for (int j4 = 0; j4 < 8; ++j4) {
      float4 w = wr[j4];
      h2[4 * j4 + 0] = fmaf(v, w.x, h2[4 * j4 + 0]);
      h2[4 * j4 + 1] = fmaf(v, w.y, h2[4 * j4 + 1]);
      h2[4 * j4 + 2] = fmaf(v, w.z, h2[4 * j4 + 2]);
      h2[4 * j4 + 3] = fmaf(v, w.w, h2[4 * j4 + 3]);
    }
  }

  // in-place store: reads of this row (both lanes of the pair, same wave)
  // complete before either lane's stores issue (wave lockstep + program order)
  float4* hop = (float4*)(h_n + n * HF + jbase);
#pragma unroll
  for (int j4 = 0; j4 < 8; ++j4)
    hop[j4] = make_float4(h2[4 * j4], h2[4 * j4 + 1], h2[4 * j4 + 2], h2[4 * j4 + 3]);
}

// ---------------------------------------------------------------------------
// out = h_n @ Wfc + bfc              [N,64]@[64,8]
// ---------------------------------------------------------------------------
__global__ void __launch_bounds__(256) out_kernel(
    const float* __restrict__ h_n, const float* __restrict__ Wfc,
    const float* __restrict__ bfc, float* __restrict__ out) {
  __shared__ float sW[HF * NC];
  __shared__ float sB[NC];
  for (int idx = threadIdx.x; idx < HF * NC; idx += 256) sW[idx] = Wfc[idx];
  if (threadIdx.x < NC) sB[threadIdx.x] = bfc[threadIdx.x];
  __syncthreads();
  int n = blockIdx.x * 256 + threadIdx.x;
  if (n >= N_NODES) return;
  float o[NC];
#pragma unroll
  for (int c = 0; c < NC; ++c) o[c] = sB[c];
  const float4* hp = (const float4*)(h_n + n * HF);
  for (int j4 = 0; j4 < HF / 4; ++j4) {
    float4 hv = hp[j4];
    float hv4[4] = {hv.x, hv.y, hv.z, hv.w};
#pragma unroll
    for (int t = 0; t < 4; ++t) {
      const float4* wr = (const float4*)(sW + (4 * j4 + t) * NC);
#pragma unroll
      for (int c4 = 0; c4 < 2; ++c4) {
        float4 w = wr[c4];
        o[4 * c4 + 0] = fmaf(hv4[t], w.x, o[4 * c4 + 0]);
        o[4 * c4 + 1] = fmaf(hv4[t], w.y, o[4 * c4 + 1]);
        o[4 * c4 + 2] = fmaf(hv4[t], w.z, o[4 * c4 + 2]);
        o[4 * c4 + 3] = fmaf(hv4[t], w.w, o[4 * c4 + 3]);
      }
    }
  }
  float4* op = (float4*)(out + n * NC);
  op[0] = make_float4(o[0], o[1], o[2], o[3]);
  op[1] = make_float4(o[4], o[5], o[6], o[7]);
}

extern "C" void kernel_launch(void* const* d_in, const int* in_sizes, int n_in,
                              void* d_out, int out_size, void* d_ws, size_t ws_size,
                              hipStream_t stream) {
  const float* node_feat = (const float*)d_in[0];
  const float* edge_feat = (const float*)d_in[1];
  const int*   src       = (const int*)d_in[2];
  const int*   dst       = (const int*)d_in[3];
  const float* Wn  = (const float*)d_in[4];
  const float* bn  = (const float*)d_in[5];
  const float* We  = (const float*)d_in[6];
  const float* be  = (const float*)d_in[7];
  const float* Wem = (const float*)d_in[8];
  const float* bem = (const float*)d_in[9];
  const float* Wnm = (const float*)d_in[10];
  const float* bnm = (const float*)d_in[11];
  const float* Wfc = (const float*)d_in[12];
  const float* bfc = (const float*)d_in[13];
  float* out = (float*)d_out;

  float* ws    = (float*)d_ws;
  float* h_n   = ws;                        // 1,920,000 f
  float* e_ws  = h_n + N_NODES * HF;        // 3,840,000 f
  float* s0    = e_ws + N_EDGES * EF;       //   480,000 f
  float* s1    = s0 + N_NODES * EF;         //   480,000 f
  float* deg   = s1 + N_NODES * EF;         //    30,000 f
  float* Wcomb = deg + N_NODES;             //       256 f
  float* bcomb = Wcomb + EF * EF;           //        16 f
  float* Wnc   = bcomb + EF;                //       512 f
  float* bvec  = Wnc + EF * NF;             //        32 f
  float* sbuf[2] = {s0, s1};

  const int EB  = (N_EDGES + 255) / 256;          // 938
  const int NB  = (N_NODES + 255) / 256;          // 118
  const int NB2 = (2 * N_NODES + 255) / 256;      // 235

  hipMemsetAsync(s0, 0, (size_t)N_NODES * EF * sizeof(float), stream);
  hipMemsetAsync(deg, 0, (size_t)N_NODES * sizeof(float), stream);
  precompute_kernel<<<1, 256, 0, stream>>>(We, be, Wem, bem, Wnm,
                                           Wcomb, bcomb, Wnc, bvec);
  scatter_init_kernel<<<EB, 256, 0, stream>>>(edge_feat, dst, s0, deg);
  node_init_kernel<<<NB2, 256, 0, stream>>>(node_feat, Wn, bn, h_n);

  // 13 reference iterations reduce to 11 edge passes + 12 node passes
  // (iter-13 updates are dead; iter-12 edge update only feeds its scatter).
  for (int i = 1; i <= 12; ++i) {
    if (i <= 11) {
      float* s_next = sbuf[i & 1];
      hipMemsetAsync(s_next, 0, (size_t)N_NODES * EF * sizeof(float), stream);
      edge_kernel<<<EB, 256, 0, stream>>>(
          (i == 1) ? edge_feat : e_ws, e_ws, h_n, src, dst,
          Wem, Wcomb, bcomb, sbuf[i & 1]);
    }
    node_kernel<<<NB2, 256, 0, stream>>>(
        h_n, sbuf[(i - 1) & 1], deg, Wnm, Wn, bn, bnm, Wnc, bvec);
  }

  out_kernel<<<NB, 256, 0, stream>>>(h_n, Wfc, bfc, out);
}

// Round 3
// 574.059 us; speedup vs baseline: 10.3581x; 5.6077x over previous
//
#include <hip/hip_runtime.h>

#define N_NODES 30000
#define N_EDGES 240000
#define NF 32
#define EF 16
#define HF 64
#define NC 8

// wbuf layout (float offsets)
#define W_COMB 0      // [16][16] We @ Wem[64:128)
#define B_COMB 256    // [16]     bem + be@Wem[64:128)
#define W_NC   272    // [16][32] We @ Wnm[0:64)
#define B_VEC  784    // [32]     be @ Wnm[0:64)
#define W_SD   816    // [32][32] cols 0-15: Wn@Wem[0:64) ; cols 16-31: Wn@Wem[128:192)
#define W_NB   1840   // [32][32] Wn @ Wnm[64:128)
#define B_SD   2864   // [32]     [bn@WemS | bn@WemD]
#define B_NB   2896   // [32]     bnm + bn@Wnm[64:128)
#define W_NF   2928   // [32][8]  Wn @ Wfc
#define B_NF   3184   // [8]      bfc + bn@Wfc

__device__ __forceinline__ float sigmoidf_(float x) {
  return 1.0f / (1.0f + __expf(-x));
}

// ---------------------------------------------------------------------------
__global__ void __launch_bounds__(256) hist_kernel(
    const int* __restrict__ dst, int* __restrict__ cnt) {
  int e = blockIdx.x * 256 + threadIdx.x;
  if (e < N_EDGES) atomicAdd(&cnt[dst[e]], 1);
}

// exclusive scan of cnt[30000] -> off[30001], cursor = copy of off
__global__ void __launch_bounds__(1024) scan_kernel(
    const int* __restrict__ cnt, int* __restrict__ off, int* __restrict__ cursor) {
  __shared__ int part[1024];
  int t = threadIdx.x;
  const int CH = (N_NODES + 1023) / 1024;   // 30
  int base = t * CH;
  int lc[CH];
  int sum = 0;
  for (int i = 0; i < CH; ++i) {
    int idx = base + i;
    lc[i] = (idx < N_NODES) ? cnt[idx] : 0;
    sum += lc[i];
  }
  part[t] = sum;
  __syncthreads();
  for (int ofs = 1; ofs < 1024; ofs <<= 1) {
    int v = (t >= ofs) ? part[t - ofs] : 0;
    __syncthreads();
    part[t] += v;
    __syncthreads();
  }
  int run = (t == 0) ? 0 : part[t - 1];
  for (int i = 0; i < CH; ++i) {
    int idx = base + i;
    if (idx < N_NODES) {
      off[idx] = run;
      cursor[idx] = run;
      run += lc[i];
    }
  }
  if (t == 1023) off[N_NODES] = part[1023];
}

__global__ void __launch_bounds__(256) scatter_kernel(
    const float* __restrict__ edge_feat, const int* __restrict__ src,
    const int* __restrict__ dst, int* __restrict__ cursor,
    unsigned short* __restrict__ src_s, unsigned short* __restrict__ dst_s,
    float* __restrict__ e_buf) {
  int e = blockIdx.x * 256 + threadIdx.x;
  if (e >= N_EDGES) return;
  int d = dst[e];
  int pos = atomicAdd(&cursor[d], 1);
  src_s[pos] = (unsigned short)src[e];
  dst_s[pos] = (unsigned short)d;
  const float4* ep = (const float4*)(edge_feat + (size_t)e * EF);
  float4* op = (float4*)(e_buf + (size_t)pos * EF);
  op[0] = ep[0]; op[1] = ep[1]; op[2] = ep[2]; op[3] = ep[3];
}

// ---------------------------------------------------------------------------
__global__ void __launch_bounds__(256) precompute_kernel(
    const float* __restrict__ Wn, const float* __restrict__ bn,
    const float* __restrict__ We, const float* __restrict__ be,
    const float* __restrict__ Wem, const float* __restrict__ bem,
    const float* __restrict__ Wnm, const float* __restrict__ bnm,
    const float* __restrict__ Wfc, const float* __restrict__ bfc,
    float* __restrict__ wbuf) {
  int tid = threadIdx.x;
  {  // Wcomb
    int r = tid >> 4, c = tid & 15;
    float acc = 0.f;
    for (int j = 0; j < HF; ++j) acc = fmaf(We[r * HF + j], Wem[(HF + j) * EF + c], acc);
    wbuf[W_COMB + tid] = acc;
  }
  for (int idx = tid; idx < EF * NF; idx += 256) {  // Wnc
    int r = idx >> 5, c = idx & 31;
    float acc = 0.f;
    for (int j = 0; j < HF; ++j) acc = fmaf(We[r * HF + j], Wnm[j * NF + c], acc);
    wbuf[W_NC + idx] = acc;
  }
  for (int idx = tid; idx < NF * NF; idx += 256) {  // WSD
    int r = idx >> 5, c = idx & 31;
    float acc = 0.f;
    if (c < EF) {
      for (int j = 0; j < HF; ++j) acc = fmaf(Wn[r * HF + j], Wem[j * EF + c], acc);
    } else {
      int cc = c - EF;
      for (int j = 0; j < HF; ++j) acc = fmaf(Wn[r * HF + j], Wem[(2 * HF + j) * EF + cc], acc);
    }
    wbuf[W_SD + idx] = acc;
  }
  for (int idx = tid; idx < NF * NF; idx += 256) {  // WnB
    int r = idx >> 5, c = idx & 31;
    float acc = 0.f;
    for (int j = 0; j < HF; ++j) acc = fmaf(Wn[r * HF + j], Wnm[(HF + j) * NF + c], acc);
    wbuf[W_NB + idx] = acc;
  }
  if (tid < NF * NC) {  // Wnf
    int r = tid >> 3, c = tid & 7;
    float acc = 0.f;
    for (int j = 0; j < HF; ++j) acc = fmaf(Wn[r * HF + j], Wfc[j * NC + c], acc);
    wbuf[W_NF + tid] = acc;
  }
  if (tid < EF) {  // bcomb
    float acc = bem[tid];
    for (int j = 0; j < HF; ++j) acc = fmaf(be[j], Wem[(HF + j) * EF + tid], acc);
    wbuf[B_COMB + tid] = acc;
  }
  if (tid < NF) {  // bvec
    float acc = 0.f;
    for (int j = 0; j < HF; ++j) acc = fmaf(be[j], Wnm[j * NF + tid], acc);
    wbuf[B_VEC + tid] = acc;
  }
  if (tid < NF) {  // bSD
    float acc = 0.f;
    if (tid < EF) {
      for (int j = 0; j < HF; ++j) acc = fmaf(bn[j], Wem[j * EF + tid], acc);
    } else {
      int cc = tid - EF;
      for (int j = 0; j < HF; ++j) acc = fmaf(bn[j], Wem[(2 * HF + j) * EF + cc], acc);
    }
    wbuf[B_SD + tid] = acc;
  }
  if (tid < NF) {  // bNB
    float acc = bnm[tid];
    for (int j = 0; j < HF; ++j) acc = fmaf(bn[j], Wnm[(HF + j) * NF + tid], acc);
    wbuf[B_NB + tid] = acc;
  }
  if (tid < NC) {  // bnf
    float acc = bfc[tid];
    for (int j = 0; j < HF; ++j) acc = fmaf(bn[j], Wfc[j * NC + tid], acc);
    wbuf[B_NF + tid] = acc;
  }
}

// ---------------------------------------------------------------------------
// init: from node_feat (no sigmoid): [P_s|P_d] = x@WSD + bSD ; hpart = x@WnB + bNB
// 2 threads/node, p = lane&1 selects which projection half this thread emits.
// ---------------------------------------------------------------------------
__global__ void __launch_bounds__(256) init_proj_kernel(
    const float* __restrict__ node_feat, const float* __restrict__ wbuf,
    float* __restrict__ Ps, float* __restrict__ Pd, float* __restrict__ hpart) {
  __shared__ float sPRJ[2048];
  __shared__ float sPB[64];
  for (int i = threadIdx.x; i < 2048; i += 256) sPRJ[i] = wbuf[W_SD + i];
  if (threadIdx.x < 64) sPB[threadIdx.x] = wbuf[B_SD + threadIdx.x];
  __syncthreads();
  int gid = blockIdx.x * 256 + threadIdx.x;
  int n = gid >> 1, p = gid & 1;
  if (n >= N_NODES) return;
  float x[NF];
  const float4* xp = (const float4*)(node_feat + (size_t)n * NF);
#pragma unroll
  for (int k4 = 0; k4 < 8; ++k4) {
    float4 v = xp[k4];
    x[4 * k4] = v.x; x[4 * k4 + 1] = v.y; x[4 * k4 + 2] = v.z; x[4 * k4 + 3] = v.w;
  }
  float pr[NF];
  const float* pb = sPB + p * 32;
#pragma unroll
  for (int j = 0; j < NF; ++j) pr[j] = pb[j];
  const float* wbase = sPRJ + p * 1024;
  for (int k = 0; k < NF; ++k) {
    float v = x[k];
    const float4* wr = (const float4*)(wbase + k * NF);
#pragma unroll
    for (int j4 = 0; j4 < 8; ++j4) {
      float4 w = wr[j4];
      pr[4 * j4 + 0] = fmaf(v, w.x, pr[4 * j4 + 0]);
      pr[4 * j4 + 1] = fmaf(v, w.y, pr[4 * j4 + 1]);
      pr[4 * j4 + 2] = fmaf(v, w.z, pr[4 * j4 + 2]);
      pr[4 * j4 + 3] = fmaf(v, w.w, pr[4 * j4 + 3]);
    }
  }
  if (p == 0) {
    float4* a = (float4*)(Ps + (size_t)n * EF);
    a[0] = make_float4(pr[0], pr[1], pr[2], pr[3]);
    a[1] = make_float4(pr[4], pr[5], pr[6], pr[7]);
    a[2] = make_float4(pr[8], pr[9], pr[10], pr[11]);
    a[3] = make_float4(pr[12], pr[13], pr[14], pr[15]);
    float4* b = (float4*)(Pd + (size_t)n * EF);
    b[0] = make_float4(pr[16], pr[17], pr[18], pr[19]);
    b[1] = make_float4(pr[20], pr[21], pr[22], pr[23]);
    b[2] = make_float4(pr[24], pr[25], pr[26], pr[27]);
    b[3] = make_float4(pr[28], pr[29], pr[30], pr[31]);
  } else {
    float4* h = (float4*)(hpart + (size_t)n * NF);
#pragma unroll
    for (int j4 = 0; j4 < 8; ++j4)
      h[j4] = make_float4(pr[4 * j4], pr[4 * j4 + 1], pr[4 * j4 + 2], pr[4 * j4 + 3]);
  }
}

// ---------------------------------------------------------------------------
// node pass i (1..11): z = hpart + deg*bvec + segsum(e)@Wnc ; sig = sigmoid(z)
// then emit next-iter projections: [Ps|Pd] = sig@WSD+bSD ; hpart' = sig@WnB+bNB
// ---------------------------------------------------------------------------
__global__ void __launch_bounds__(256) node_kernel(
    const float* __restrict__ e_buf, float* __restrict__ hpart,
    const int* __restrict__ off, const float* __restrict__ wbuf,
    float* __restrict__ Ps_next, float* __restrict__ Pd_next) {
  __shared__ float sWnc[EF * NF];
  __shared__ float sbvec[NF];
  __shared__ float sPRJ[2048];
  __shared__ float sPB[64];
  for (int i = threadIdx.x; i < 2048; i += 256) sPRJ[i] = wbuf[W_SD + i];
  for (int i = threadIdx.x; i < EF * NF; i += 256) sWnc[i] = wbuf[W_NC + i];
  if (threadIdx.x < 64) sPB[threadIdx.x] = wbuf[B_SD + threadIdx.x];
  if (threadIdx.x < NF) sbvec[threadIdx.x] = wbuf[B_VEC + threadIdx.x];
  __syncthreads();
  int gid = blockIdx.x * 256 + threadIdx.x;
  int n = gid >> 1, p = gid & 1;
  if (n >= N_NODES) return;
  int o0 = off[n], o1 = off[n + 1];

  float s8[8] = {0, 0, 0, 0, 0, 0, 0, 0};
  for (int q = o0; q < o1; ++q) {
    const float4* ep = (const float4*)(e_buf + (size_t)q * EF + 8 * p);
    float4 a = ep[0], b = ep[1];
    s8[0] += a.x; s8[1] += a.y; s8[2] += a.z; s8[3] += a.w;
    s8[4] += b.x; s8[5] += b.y; s8[6] += b.z; s8[7] += b.w;
  }

  float z[NF];
  if (p == 0) {
    const float4* hp = (const float4*)(hpart + (size_t)n * NF);
#pragma unroll
    for (int j4 = 0; j4 < 8; ++j4) {
      float4 v = hp[j4];
      z[4 * j4] = v.x; z[4 * j4 + 1] = v.y; z[4 * j4 + 2] = v.z; z[4 * j4 + 3] = v.w;
    }
  } else {
    float dg = (float)(o1 - o0);
#pragma unroll
    for (int j = 0; j < NF; ++j) z[j] = dg * sbvec[j];
  }
#pragma unroll
  for (int k = 0; k < 8; ++k) {
    float v = s8[k];
    const float4* wr = (const float4*)(sWnc + (8 * p + k) * NF);
#pragma unroll
    for (int j4 = 0; j4 < 8; ++j4) {
      float4 w = wr[j4];
      z[4 * j4 + 0] = fmaf(v, w.x, z[4 * j4 + 0]);
      z[4 * j4 + 1] = fmaf(v, w.y, z[4 * j4 + 1]);
      z[4 * j4 + 2] = fmaf(v, w.z, z[4 * j4 + 2]);
      z[4 * j4 + 3] = fmaf(v, w.w, z[4 * j4 + 3]);
    }
  }
#pragma unroll
  for (int j = 0; j < NF; ++j) z[j] += __shfl_xor(z[j], 1, 64);
#pragma unroll
  for (int j = 0; j < NF; ++j) z[j] = sigmoidf_(z[j]);

  float pr[NF];
  const float* pb = sPB + p * 32;
#pragma unroll
  for (int j = 0; j < NF; ++j) pr[j] = pb[j];
  const float* wbase = sPRJ + p * 1024;
  for (int k = 0; k < NF; ++k) {
    float v = z[k];
    const float4* wr = (const float4*)(wbase + k * NF);
#pragma unroll
    for (int j4 = 0; j4 < 8; ++j4) {
      float4 w = wr[j4];
      pr[4 * j4 + 0] = fmaf(v, w.x, pr[4 * j4 + 0]);
      pr[4 * j4 + 1] = fmaf(v, w.y, pr[4 * j4 + 1]);
      pr[4 * j4 + 2] = fmaf(v, w.z, pr[4 * j4 + 2]);
      pr[4 * j4 + 3] = fmaf(v, w.w, pr[4 * j4 + 3]);
    }
  }
  if (p == 0) {
    float4* a = (float4*)(Ps_next + (size_t)n * EF);
    a[0] = make_float4(pr[0], pr[1], pr[2], pr[3]);
    a[1] = make_float4(pr[4], pr[5], pr[6], pr[7]);
    a[2] = make_float4(pr[8], pr[9], pr[10], pr[11]);
    a[3] = make_float4(pr[12], pr[13], pr[14], pr[15]);
    float4* b = (float4*)(Pd_next + (size_t)n * EF);
    b[0] = make_float4(pr[16], pr[17], pr[18], pr[19]);
    b[1] = make_float4(pr[20], pr[21], pr[22], pr[23]);
    b[2] = make_float4(pr[24], pr[25], pr[26], pr[27]);
    b[3] = make_float4(pr[28], pr[29], pr[30], pr[31]);
  } else {
    float4* h = (float4*)(hpart + (size_t)n * NF);
#pragma unroll
    for (int j4 = 0; j4 < 8; ++j4)
      h[j4] = make_float4(pr[4 * j4], pr[4 * j4 + 1], pr[4 * j4 + 2], pr[4 * j4 + 3]);
  }
}

// ---------------------------------------------------------------------------
// final node pass (iter 12): z/sig as above, then out = sig @ Wnf + bnf
// ---------------------------------------------------------------------------
__global__ void __launch_bounds__(256) final_kernel(
    const float* __restrict__ e_buf, const float* __restrict__ hpart,
    const int* __restrict__ off, const float* __restrict__ wbuf,
    float* __restrict__ out) {
  __shared__ float sWnc[EF * NF];
  __shared__ float sbvec[NF];
  __shared__ float sWNF[NF * NC];
  __shared__ float sBNF[NC];
  for (int i = threadIdx.x; i < EF * NF; i += 256) sWnc[i] = wbuf[W_NC + i];
  if (threadIdx.x < NF) sbvec[threadIdx.x] = wbuf[B_VEC + threadIdx.x];
  if (threadIdx.x < NF * NC) sWNF[threadIdx.x] = wbuf[W_NF + threadIdx.x];
  if (threadIdx.x < NC) sBNF[threadIdx.x] = wbuf[B_NF + threadIdx.x];
  __syncthreads();
  int gid = blockIdx.x * 256 + threadIdx.x;
  int n = gid >> 1, p = gid & 1;
  if (n >= N_NODES) return;
  int o0 = off[n], o1 = off[n + 1];

  float s8[8] = {0, 0, 0, 0, 0, 0, 0, 0};
  for (int q = o0; q < o1; ++q) {
    const float4* ep = (const float4*)(e_buf + (size_t)q * EF + 8 * p);
    float4 a = ep[0], b = ep[1];
    s8[0] += a.x; s8[1] += a.y; s8[2] += a.z; s8[3] += a.w;
    s8[4] += b.x; s8[5] += b.y; s8[6] += b.z; s8[7] += b.w;
  }
  float z[NF];
  if (p == 0) {
    const float4* hp = (const float4*)(hpart + (size_t)n * NF);
#pragma unroll
    for (int j4 = 0; j4 < 8; ++j4) {
      float4 v = hp[j4];
      z[4 * j4] = v.x; z[4 * j4 + 1] = v.y; z[4 * j4 + 2] = v.z; z[4 * j4 + 3] = v.w;
    }
  } else {
    float dg = (float)(o1 - o0);
#pragma unroll
    for (int j = 0; j < NF; ++j) z[j] = dg * sbvec[j];
  }
#pragma unroll
  for (int k = 0; k < 8; ++k) {
    float v = s8[k];
    const float4* wr = (const float4*)(sWnc + (8 * p + k) * NF);
#pragma unroll
    for (int j4 = 0; j4 < 8; ++j4) {
      float4 w = wr[j4];
      z[4 * j4 + 0] = fmaf(v, w.x, z[4 * j4 + 0]);
      z[4 * j4 + 1] = fmaf(v, w.y, z[4 * j4 + 1]);
      z[4 * j4 + 2] = fmaf(v, w.z, z[4 * j4 + 2]);
      z[4 * j4 + 3] = fmaf(v, w.w, z[4 * j4 + 3]);
    }
  }
#pragma unroll
  for (int j = 0; j < NF; ++j) z[j] += __shfl_xor(z[j], 1, 64);
#pragma unroll
  for (int j = 0; j < NF; ++j) z[j] = sigmoidf_(z[j]);

  float o[NC];
  float pm = (p == 0) ? 1.0f : 0.0f;
#pragma unroll
  for (int c = 0; c < NC; ++c) o[c] = pm * sBNF[c];
  for (int k = 0; k < 16; ++k) {
    float v = z[16 * p + k];
    const float* wr = sWNF + (16 * p + k) * NC;
#pragma unroll
    for (int c = 0; c < NC; ++c) o[c] = fmaf(v, wr[c], o[c]);
  }
#pragma unroll
  for (int c = 0; c < NC; ++c) o[c] += __shfl_xor(o[c], 1, 64);
  if (p == 0) {
    float4* op = (float4*)(out + (size_t)n * NC);
    op[0] = make_float4(o[0], o[1], o[2], o[3]);
    op[1] = make_float4(o[4], o[5], o[6], o[7]);
  }
}

// ---------------------------------------------------------------------------
// edge pass i (1..11), sorted order, in-place on e_buf:
//   z = bcomb + e@Wcomb + Ps[src] + Pd[dst] ; e' = sigmoid(z)
// ---------------------------------------------------------------------------
__global__ void __launch_bounds__(256) edge_kernel(
    float* __restrict__ e_buf, const unsigned short* __restrict__ src_s,
    const unsigned short* __restrict__ dst_s,
    const float* __restrict__ Ps, const float* __restrict__ Pd,
    const float* __restrict__ wbuf) {
  __shared__ float sWC[EF * EF];
  __shared__ float sBC[EF];
  sWC[threadIdx.x] = wbuf[W_COMB + threadIdx.x];
  if (threadIdx.x < EF) sBC[threadIdx.x] = wbuf[B_COMB + threadIdx.x];
  __syncthreads();
  int q = blockIdx.x * 256 + threadIdx.x;
  if (q >= N_EDGES) return;
  int s = src_s[q], d = dst_s[q];

  float e[EF];
  float4* ebp = (float4*)(e_buf + (size_t)q * EF);
#pragma unroll
  for (int k4 = 0; k4 < 4; ++k4) {
    float4 v = ebp[k4];
    e[4 * k4] = v.x; e[4 * k4 + 1] = v.y; e[4 * k4 + 2] = v.z; e[4 * k4 + 3] = v.w;
  }
  const float4* ps = (const float4*)(Ps + (size_t)s * EF);
  const float4* pd = (const float4*)(Pd + (size_t)d * EF);
  float z[EF];
#pragma unroll
  for (int i4 = 0; i4 < 4; ++i4) {
    float4 a = ps[i4], b = pd[i4];
    z[4 * i4 + 0] = sBC[4 * i4 + 0] + a.x + b.x;
    z[4 * i4 + 1] = sBC[4 * i4 + 1] + a.y + b.y;
    z[4 * i4 + 2] = sBC[4 * i4 + 2] + a.z + b.z;
    z[4 * i4 + 3] = sBC[4 * i4 + 3] + a.w + b.w;
  }
#pragma unroll
  for (int k = 0; k < EF; ++k) {
    float v = e[k];
    const float4* wr = (const float4*)(sWC + k * EF);
#pragma unroll
    for (int i4 = 0; i4 < 4; ++i4) {
      float4 w = wr[i4];
      z[4 * i4 + 0] = fmaf(v, w.x, z[4 * i4 + 0]);
      z[4 * i4 + 1] = fmaf(v, w.y, z[4 * i4 + 1]);
      z[4 * i4 + 2] = fmaf(v, w.z, z[4 * i4 + 2]);
      z[4 * i4 + 3] = fmaf(v, w.w, z[4 * i4 + 3]);
    }
  }
#pragma unroll
  for (int i = 0; i < EF; ++i) z[i] = sigmoidf_(z[i]);
#pragma unroll
  for (int i4 = 0; i4 < 4; ++i4)
    ebp[i4] = make_float4(z[4 * i4], z[4 * i4 + 1], z[4 * i4 + 2], z[4 * i4 + 3]);
}

// ---------------------------------------------------------------------------
extern "C" void kernel_launch(void* const* d_in, const int* in_sizes, int n_in,
                              void* d_out, int out_size, void* d_ws, size_t ws_size,
                              hipStream_t stream) {
  const float* node_feat = (const float*)d_in[0];
  const float* edge_feat = (const float*)d_in[1];
  const int*   src = (const int*)d_in[2];
  const int*   dst = (const int*)d_in[3];
  const float* Wn  = (const float*)d_in[4];
  const float* bn  = (const float*)d_in[5];
  const float* We  = (const float*)d_in[6];
  const float* be  = (const float*)d_in[7];
  const float* Wem = (const float*)d_in[8];
  const float* bem = (const float*)d_in[9];
  const float* Wnm = (const float*)d_in[10];
  const float* bnm = (const float*)d_in[11];
  const float* Wfc = (const float*)d_in[12];
  const float* bfc = (const float*)d_in[13];
  float* out = (float*)d_out;

  float* ws    = (float*)d_ws;
  float* e_buf = ws;                                   // 3,840,000 f
  float* hpart = e_buf + (size_t)N_EDGES * EF;         //   960,000 f
  float* Ps0   = hpart + (size_t)N_NODES * NF;         //   480,000 f
  float* Pd0   = Ps0 + (size_t)N_NODES * EF;
  float* Ps1   = Pd0 + (size_t)N_NODES * EF;
  float* Pd1   = Ps1 + (size_t)N_NODES * EF;
  float* wbuf  = Pd1 + (size_t)N_NODES * EF;           //     4,096 f (3192 used)
  int* cnt     = (int*)(wbuf + 4096);                  //    30,000 i
  int* off     = cnt + N_NODES;                        //    30,001 i
  int* cursor  = off + N_NODES + 1;                    //    30,000 i
  unsigned short* src_s = (unsigned short*)(cursor + N_NODES);  // 240,000 u16
  unsigned short* dst_s = src_s + N_EDGES;                      // 240,000 u16
  float* PsA[2] = {Ps0, Ps1};
  float* PdA[2] = {Pd0, Pd1};

  const int EB  = (N_EDGES + 255) / 256;       // 938
  const int NB2 = (2 * N_NODES + 255) / 256;   // 235

  // --- counting sort of edges by dst (amortized over all 11 edge passes) ---
  hipMemsetAsync(cnt, 0, (size_t)N_NODES * sizeof(int), stream);
  hist_kernel<<<EB, 256, 0, stream>>>(dst, cnt);
  scan_kernel<<<1, 1024, 0, stream>>>(cnt, off, cursor);
  scatter_kernel<<<EB, 256, 0, stream>>>(edge_feat, src, dst, cursor,
                                         src_s, dst_s, e_buf);
  // --- fold all weight products on-device ---
  precompute_kernel<<<1, 256, 0, stream>>>(Wn, bn, We, be, Wem, bem,
                                           Wnm, bnm, Wfc, bfc, wbuf);
  // P_1 / hpart_1 from node_feat
  init_proj_kernel<<<NB2, 256, 0, stream>>>(node_feat, wbuf, Ps1, Pd1, hpart);

  // 13 reference iterations reduce to 11 edge + 12 node passes.
  // Order per iteration: node_i first (reads e-state i before edge_i
  // overwrites it in place); P ping-pong: edge_i reads P[i&1], node_i
  // writes P[(i+1)&1]; hpart updated in place by node_i.
  for (int i = 1; i <= 11; ++i) {
    node_kernel<<<NB2, 256, 0, stream>>>(e_buf, hpart, off, wbuf,
                                         PsA[(i + 1) & 1], PdA[(i + 1) & 1]);
    edge_kernel<<<EB, 256, 0, stream>>>(e_buf, src_s, dst_s,
                                        PsA[i & 1], PdA[i & 1], wbuf);
  }
  // node pass 12 fused with the output head (Wn@Wfc folded)
  final_kernel<<<NB2, 256, 0, stream>>>(e_buf, hpart, off, wbuf, out);
}